// Round 9
// baseline (294.201 us; speedup 1.0000x reference)
//
#include <hip/hip_runtime.h>

#define EPSILON 0.1f
#define F_IN 256
#define F_OUT 96
#define NF 3
#define TCOLS 288    // real columns: ii*96+f
#define TSTRIDE 320  // padded t row stride (bf16) = 640 B = 5 cache lines, line-aligned
#define CAP 64       // per-row edge bucket capacity (mean deg 16, ~12 sigma headroom)
#define BN 96        // columns per gemm block (3 col-blocks cover 288)
#define CW 104       // epilogue repack row stride (ushorts): 208 B, 16B-aligned
#define NCVT (TCOLS * F_IN / 4)   // 18432 cvt threads in setup

typedef __attribute__((ext_vector_type(8))) short bf8_t;   // 8 bf16 (4 VGPRs)
typedef __attribute__((ext_vector_type(4))) float f32x4;

__device__ inline ushort f2b(float f) {
    union { float f; unsigned u; } v; v.f = f;
    unsigned u = v.u;
    return (ushort)((u + 0x7FFFu + ((u >> 16) & 1u)) >> 16);  // RNE
}
__device__ inline float blo(unsigned u) { return __uint_as_float(u << 16); }
__device__ inline float bhi(unsigned u) { return __uint_as_float(u & 0xffff0000u); }

__device__ inline bf8_t cvt8(float4 a, float4 b) {
    bf8_t r;
    r[0] = (short)f2b(a.x); r[1] = (short)f2b(a.y);
    r[2] = (short)f2b(a.z); r[3] = (short)f2b(a.w);
    r[4] = (short)f2b(b.x); r[5] = (short)f2b(b.y);
    r[6] = (short)f2b(b.z); r[7] = (short)f2b(b.w);
    return r;
}

// ---------------- setup: W convert/transpose + zero cnt ----------------
// wt[gc][k] = bf16(w[ii][k][f]), gc = ii*96+f
__global__ __launch_bounds__(256) void setup_kernel(const float* __restrict__ w,
                                                    ushort* __restrict__ wt,
                                                    int* __restrict__ cnt, int N) {
    int tid = blockIdx.x * 256 + threadIdx.x;
    if (tid < NCVT) {
        int base = tid * 4;
        int gc = base >> 8;
        int k  = base & 255;
        int ii = gc / F_OUT;
        int c  = gc - ii * F_OUT;
        const float* wp = w + (size_t)ii * (F_IN * F_OUT) + (size_t)k * F_OUT + c;
        ushort4 o;
        o.x = f2b(wp[0 * F_OUT]);
        o.y = f2b(wp[1 * F_OUT]);
        o.z = f2b(wp[2 * F_OUT]);
        o.w = f2b(wp[3 * F_OUT]);
        *(ushort4*)(wt + base) = o;
    } else {
        int z = (tid - NCVT) * 4;
        if (z + 3 < N) {
            *(int4*)(cnt + z) = make_int4(0, 0, 0, 0);
        } else {
            for (int j = z; j < N && j >= 0; ++j) cnt[j] = 0;
        }
    }
}

// ---------------- one-pass bucket scatter (zero LDS, high occupancy) ----------------
__global__ __launch_bounds__(256) void scatter_kernel(const int* __restrict__ row,
                                                      const int* __restrict__ col,
                                                      const float* __restrict__ vals,
                                                      int* __restrict__ cnt,
                                                      int2* __restrict__ evs2, int E) {
    int i0 = (blockIdx.x * 256 + threadIdx.x) * 4;
    if (i0 + 3 < E) {
        int4   r4 = *(const int4*)(row + i0);
        int4   c4 = *(const int4*)(col + i0);
        float4 v4 = *(const float4*)(vals + i0);
        int k;
        k = atomicAdd(&cnt[r4.x], 1);
        if (k < CAP) evs2[(size_t)r4.x * CAP + k] = make_int2(c4.x, __float_as_int(v4.x));
        k = atomicAdd(&cnt[r4.y], 1);
        if (k < CAP) evs2[(size_t)r4.y * CAP + k] = make_int2(c4.y, __float_as_int(v4.y));
        k = atomicAdd(&cnt[r4.z], 1);
        if (k < CAP) evs2[(size_t)r4.z * CAP + k] = make_int2(c4.z, __float_as_int(v4.z));
        k = atomicAdd(&cnt[r4.w], 1);
        if (k < CAP) evs2[(size_t)r4.w * CAP + k] = make_int2(c4.w, __float_as_int(v4.w));
    } else {
        for (int i = i0; i < E; ++i) {
            int r = row[i];
            int k = atomicAdd(&cnt[r], 1);
            if (k < CAP) evs2[(size_t)r * CAP + k] = make_int2(col[i], __float_as_int(vals[i]));
        }
    }
}

// ---------------- MFMA GEMM: B-slice staged ONCE, barrier-free K-loop ----------------
// Grid = 3 col-blocks x ceil(N/64). Per block: 96 cols x 64 rows, 4 waves x 16 rows.
// Bs holds the full 96x256 B-slice in FRAGMENT-MAJOR order: chunk F=(ks*6+j)*64+lane
// -> every ds_read_b128 is lane-linear (conflict-free). One barrier after staging,
// one before the epilogue repack. A streamed register-direct with 1-deep prefetch.
__global__ __launch_bounds__(256) void gemm_mfma(const float* __restrict__ x,
                                                 const ushort* __restrict__ wt,
                                                 const float* __restrict__ dsc,
                                                 ushort* __restrict__ t, int N) {
    __shared__ ushort Bs[BN * F_IN];   // 49152 B; reused for epilogue repack

    int tid = threadIdx.x;
    int lane = tid & 63, wave = tid >> 6;
    int cl = lane & 15, quad = lane >> 4;
    int mb = blockIdx.x / 3, cb = blockIdx.x - mb * 3;
    int gc0 = cb * BN;
    int m0 = mb * 64 + wave * 16;
    int mrow = m0 + cl;
    bool aok = (mrow < N);

    // stage B slice: 96 rows x 256 k = 3072 uint4 chunks, 12 per thread, fragment-major
    #pragma unroll
    for (int i = 0; i < 12; ++i) {
        int F = tid + i * 256;          // 0..3071
        int rem = F & 63;
        int q = rem >> 4, c = rem & 15;
        int ksj = F >> 6;               // 0..47
        int ks = ksj / 6, j = ksj - ks * 6;
        int gc = gc0 + j * 16 + c;
        *(uint4*)(Bs + (size_t)F * 8) =
            *(const uint4*)(wt + (size_t)gc * F_IN + ks * 32 + q * 8);
    }

    f32x4 acc[6];
    #pragma unroll
    for (int j = 0; j < 6; ++j) acc[j] = (f32x4){0.f, 0.f, 0.f, 0.f};

    const float* xp = x + (size_t)mrow * F_IN + quad * 8;
    const float4 fz = make_float4(0.f, 0.f, 0.f, 0.f);
    float4 pa0 = aok ? *(const float4*)(xp)     : fz;
    float4 pa1 = aok ? *(const float4*)(xp + 4) : fz;

    __syncthreads();   // B staged

    #pragma unroll
    for (int ks = 0; ks < 8; ++ks) {
        bf8_t a = cvt8(pa0, pa1);
        if (ks < 7) {   // prefetch next K=32 chunk of A
            pa0 = aok ? *(const float4*)(xp + (ks + 1) * 32)     : fz;
            pa1 = aok ? *(const float4*)(xp + (ks + 1) * 32 + 4) : fz;
        }
        const ushort* bb = Bs + ((size_t)(ks * 6) * 64 + lane) * 8;
        #pragma unroll
        for (int j = 0; j < 6; ++j) {
            bf8_t b = *(const bf8_t*)(bb + j * 64 * 8);
            acc[j] = __builtin_amdgcn_mfma_f32_16x16x32_bf16(a, b, acc[j], 0, 0, 0);
        }
    }

    // epilogue: C/D layout col=cl, row=quad*4+reg. Scale, cvt, repack via LDS.
    __syncthreads();   // all B reads done before alias overwrite
    ushort* Cw = Bs + wave * (16 * CW);
    float dscv[3][4];
    #pragma unroll
    for (int ii = 0; ii < 3; ++ii)
        #pragma unroll
        for (int r = 0; r < 4; ++r) {
            int rowg = m0 + quad * 4 + r;
            dscv[ii][r] = (rowg < N) ? dsc[(size_t)ii * N + rowg] : 0.f;
        }
    #pragma unroll
    for (int j = 0; j < 6; ++j) {
        int ii = (gc0 + j * 16) / F_OUT;   // filter of this 16-col tile (uniform per tile)
        #pragma unroll
        for (int r = 0; r < 4; ++r)
            Cw[(quad * 4 + r) * CW + j * 16 + cl] = f2b(dscv[ii][r] * acc[j][r]);
    }
    // 16 rows x 12 chunks = 192 uint4 per wave; 3 per lane, coalesced
    #pragma unroll
    for (int it = 0; it < 3; ++it) {
        int idx = lane + it * 64;          // 0..191
        int r = idx / 12, ch = idx - r * 12;
        int grow = m0 + r;
        if (grow < N)
            *(uint4*)(t + (size_t)grow * TSTRIDE + gc0 + ch * 8) =
                *(const uint4*)&Cw[r * CW + ch * 8];
    }
}

// ---------------- fused SpMM + diagonal + relu + D + bias ----------------
// wave-per-row, 4 rows/block (R4-proven unroll-4). Lane l<40 owns uint4 chunk
// [8l,8l+8) of the padded 320-col t row. Edge records from bucket, shfl-broadcast.
__device__ inline void acc8(float* acc, uint4 a, float v) {
    acc[0] = fmaf(v, blo(a.x), acc[0]); acc[1] = fmaf(v, bhi(a.x), acc[1]);
    acc[2] = fmaf(v, blo(a.y), acc[2]); acc[3] = fmaf(v, bhi(a.y), acc[3]);
    acc[4] = fmaf(v, blo(a.z), acc[4]); acc[5] = fmaf(v, bhi(a.z), acc[5]);
    acc[6] = fmaf(v, blo(a.w), acc[6]); acc[7] = fmaf(v, bhi(a.w), acc[7]);
}

__global__ __launch_bounds__(256) void spmm_kernel(const ushort* __restrict__ t,
                                                   const int2* __restrict__ evs2,
                                                   const int* __restrict__ cnt,
                                                   const float* __restrict__ dsc,
                                                   const float* __restrict__ bias,
                                                   float* __restrict__ out, int N) {
    int lane = threadIdx.x & 63;
    int wave = threadIdx.x >> 6;
    int n = blockIdx.x * 4 + wave;
    if (n >= N) return;

    int deg = cnt[n];
    int mm = (deg < CAP) ? deg : CAP;
    int s = n * CAP, e = s + mm;
    int coff = (lane < 40) ? lane * 8 : 0;   // ushort offset of this lane's chunk

    float acc[8];
    #pragma unroll
    for (int j = 0; j < 8; ++j) acc[j] = 0.f;

    for (int base = s; base < e; base += 64) {
        int idx = base + lane;
        int2 q = make_int2(0, 0);
        if (idx < e) q = evs2[idx];
        int m = min(64, e - base);
        int j = 0;
        for (; j + 3 < m; j += 4) {
            int c0 = __shfl(q.x, j, 64);
            int c1 = __shfl(q.x, j + 1, 64);
            int c2 = __shfl(q.x, j + 2, 64);
            int c3 = __shfl(q.x, j + 3, 64);
            float v0 = __int_as_float(__shfl(q.y, j, 64));
            float v1 = __int_as_float(__shfl(q.y, j + 1, 64));
            float v2 = __int_as_float(__shfl(q.y, j + 2, 64));
            float v3 = __int_as_float(__shfl(q.y, j + 3, 64));
            uint4 a0 = *(const uint4*)(t + (size_t)c0 * TSTRIDE + coff);
            uint4 a1 = *(const uint4*)(t + (size_t)c1 * TSTRIDE + coff);
            uint4 a2 = *(const uint4*)(t + (size_t)c2 * TSTRIDE + coff);
            uint4 a3 = *(const uint4*)(t + (size_t)c3 * TSTRIDE + coff);
            acc8(acc, a0, v0);
            acc8(acc, a1, v1);
            acc8(acc, a2, v2);
            acc8(acc, a3, v3);
        }
        for (; j < m; ++j) {
            int c = __shfl(q.x, j, 64);
            float v = __int_as_float(__shfl(q.y, j, 64));
            uint4 a = *(const uint4*)(t + (size_t)c * TSTRIDE + coff);
            acc8(acc, a, v);
        }
    }

    // self term + relu + D scale (per-lane filter ii = lane/12 for lane<36)
    float sign = (lane < 12) ? -1.f : 1.f;
    float epsdi = EPSILON / (float)(deg + 1);   // deg includes self loop
    int ii = lane / 12;
    float dscv = (lane < 36) ? dsc[(size_t)ii * N + n] : 0.f;
    uint4 sv = *(const uint4*)(t + (size_t)n * TSTRIDE + coff);
    float se = sign * epsdi;
    float val[8];
    {
        unsigned u;
        u = sv.x; val[0] = fmaf(se, blo(u), acc[0]); val[1] = fmaf(se, bhi(u), acc[1]);
        u = sv.y; val[2] = fmaf(se, blo(u), acc[2]); val[3] = fmaf(se, bhi(u), acc[3]);
        u = sv.z; val[4] = fmaf(se, blo(u), acc[4]); val[5] = fmaf(se, bhi(u), acc[5]);
        u = sv.w; val[6] = fmaf(se, blo(u), acc[6]); val[7] = fmaf(se, bhi(u), acc[7]);
    }
    #pragma unroll
    for (int j = 0; j < 8; ++j) val[j] = fmaxf(val[j], 0.f) * dscv;

    // cross-filter reduce: out[8a+j] = val[a][j] + val[a+12][j] + val[a+24][j]
    float res[8];
    #pragma unroll
    for (int j = 0; j < 8; ++j) {
        float r1 = __shfl(val[j], lane + 12, 64);
        float r2 = __shfl(val[j], lane + 24, 64);
        res[j] = val[j] + r1 + r2;
    }
    if (lane < 12) {
        float4 b0 = *(const float4*)(bias + lane * 8);
        float4 b1 = *(const float4*)(bias + lane * 8 + 4);
        float4 o0 = make_float4(res[0] + b0.x, res[1] + b0.y, res[2] + b0.z, res[3] + b0.w);
        float4 o1 = make_float4(res[4] + b1.x, res[5] + b1.y, res[6] + b1.z, res[7] + b1.w);
        *(float4*)(out + (size_t)n * F_OUT + lane * 8) = o0;
        *(float4*)(out + (size_t)n * F_OUT + lane * 8 + 4) = o1;
    }
}

extern "C" void kernel_launch(void* const* d_in, const int* in_sizes, int n_in,
                              void* d_out, int out_size, void* d_ws, size_t ws_size,
                              hipStream_t stream) {
    const float* x    = (const float*)d_in[0];
    const float* adj  = (const float*)d_in[1];
    const float* dsc  = (const float*)d_in[2];
    const float* w    = (const float*)d_in[3];
    const float* bias = (const float*)d_in[4];
    const int*   ei   = (const int*)d_in[5];

    int E = in_sizes[1];
    int N = in_sizes[0] / F_IN;
    const int* row = ei;
    const int* col = ei + E;
    float* out = (float*)d_out;

    // workspace carve-up (256B aligned): ~58 MB total
    char* p = (char*)d_ws;
    auto take = [&](size_t bytes) {
        char* r = p;
        p += (bytes + 255) & ~(size_t)255;
        return r;
    };
    int*    cnt  = (int*)take((size_t)N * 4);
    int2*   evs2 = (int2*)take((size_t)N * CAP * 8);               // 25.6 MB
    ushort* wt   = (ushort*)take((size_t)TCOLS * F_IN * 2);
    ushort* t    = (ushort*)take(((size_t)N * TSTRIDE + 256) * 2); // 32 MB

    int nzero = (N + 3) / 4;
    setup_kernel<<<(NCVT + nzero + 255) / 256, 256, 0, stream>>>(w, wt, cnt, N);
    scatter_kernel<<<(E / 4 + 255) / 256, 256, 0, stream>>>(row, col, adj, cnt, evs2, E);
    gemm_mfma<<<3 * ((N + 63) / 64), 256, 0, stream>>>(x, wt, dsc, t, N);
    spmm_kernel<<<(N + 3) / 4, 256, 0, stream>>>(t, evs2, cnt, dsc, bias, out, N);
}

// Round 10
// 261.590 us; speedup vs baseline: 1.1247x; 1.1247x over previous
//
#include <hip/hip_runtime.h>

#define EPSILON 0.1f
#define F_IN 256
#define F_OUT 96
#define NF 3
#define TCOLS 288    // real columns: ii*96+f
#define TSTRIDE 320  // padded t row stride (bf16) = 640 B = 5 cache lines, line-aligned
#define CAP 64       // per-row edge bucket capacity (mean deg 16, ~12 sigma headroom)
#define BN 96        // columns per gemm block (3 col-blocks cover 288)
#define CW 104       // epilogue repack row stride (ushorts): 208 B, 16B-aligned
#define NCVT (TCOLS * F_IN / 4)   // 18432 wt-cvt threads in setup

typedef __attribute__((ext_vector_type(8))) short bf8_t;   // 8 bf16 (4 VGPRs)
typedef __attribute__((ext_vector_type(4))) float f32x4;

__device__ inline ushort f2b(float f) {
    union { float f; unsigned u; } v; v.f = f;
    unsigned u = v.u;
    return (ushort)((u + 0x7FFFu + ((u >> 16) & 1u)) >> 16);  // RNE
}
__device__ inline float blo(unsigned u) { return __uint_as_float(u << 16); }
__device__ inline float bhi(unsigned u) { return __uint_as_float(u & 0xffff0000u); }

__device__ inline bf8_t cvt8(float4 a, float4 b) {
    bf8_t r;
    r[0] = (short)f2b(a.x); r[1] = (short)f2b(a.y);
    r[2] = (short)f2b(a.z); r[3] = (short)f2b(a.w);
    r[4] = (short)f2b(b.x); r[5] = (short)f2b(b.y);
    r[6] = (short)f2b(b.z); r[7] = (short)f2b(b.w);
    return r;
}

// ---------------- setup: W convert/transpose + zero cnt ----------------
// wt[gc][k] = bf16(w[ii][k][f]), gc = ii*96+f
__global__ __launch_bounds__(256) void setup_kernel(const float* __restrict__ w,
                                                    ushort* __restrict__ wt,
                                                    int* __restrict__ cnt, int N) {
    int tid = blockIdx.x * 256 + threadIdx.x;
    if (tid < NCVT) {
        int base = tid * 4;
        int gc = base >> 8;
        int k  = base & 255;
        int ii = gc / F_OUT;
        int c  = gc - ii * F_OUT;
        const float* wp = w + (size_t)ii * (F_IN * F_OUT) + (size_t)k * F_OUT + c;
        ushort4 o;
        o.x = f2b(wp[0 * F_OUT]);
        o.y = f2b(wp[1 * F_OUT]);
        o.z = f2b(wp[2 * F_OUT]);
        o.w = f2b(wp[3 * F_OUT]);
        *(ushort4*)(wt + base) = o;
    } else {
        int z = (tid - NCVT) * 4;
        if (z + 3 < N) {
            *(int4*)(cnt + z) = make_int4(0, 0, 0, 0);
        } else {
            for (int j = z; j < N && j >= 0; ++j) cnt[j] = 0;
        }
    }
}

// ---------------- fused: one-pass bucket scatter + x->bf16 convert ----------------
// Block-range split; both paths are zero-LDS / low-VGPR so neither caps the other's
// occupancy (the R7 failure mode). Scatter blocks dispatch first (long pole, atomic
// latency); cvt blocks stream behind them.
__global__ __launch_bounds__(256) void scatter_cvt_kernel(
        const int* __restrict__ row, const int* __restrict__ col,
        const float* __restrict__ vals, int* __restrict__ cnt,
        int2* __restrict__ evs2, int E,
        const float* __restrict__ x, ushort* __restrict__ xb, int N, int nscat) {
    if ((int)blockIdx.x < nscat) {
        int i0 = (blockIdx.x * 256 + threadIdx.x) * 4;
        if (i0 + 3 < E) {
            int4   r4 = *(const int4*)(row + i0);
            int4   c4 = *(const int4*)(col + i0);
            float4 v4 = *(const float4*)(vals + i0);
            int k;
            k = atomicAdd(&cnt[r4.x], 1);
            if (k < CAP) evs2[(size_t)r4.x * CAP + k] = make_int2(c4.x, __float_as_int(v4.x));
            k = atomicAdd(&cnt[r4.y], 1);
            if (k < CAP) evs2[(size_t)r4.y * CAP + k] = make_int2(c4.y, __float_as_int(v4.y));
            k = atomicAdd(&cnt[r4.z], 1);
            if (k < CAP) evs2[(size_t)r4.z * CAP + k] = make_int2(c4.z, __float_as_int(v4.z));
            k = atomicAdd(&cnt[r4.w], 1);
            if (k < CAP) evs2[(size_t)r4.w * CAP + k] = make_int2(c4.w, __float_as_int(v4.w));
        } else {
            for (int i = i0; i < E; ++i) {
                int r = row[i];
                int k = atomicAdd(&cnt[r], 1);
                if (k < CAP) evs2[(size_t)r * CAP + k] = make_int2(col[i], __float_as_int(vals[i]));
            }
        }
    } else {
        size_t base = ((size_t)(blockIdx.x - nscat) * 256 + threadIdx.x) * 8;
        if (base < (size_t)N * F_IN) {
            float4 a = *(const float4*)(x + base);
            float4 b = *(const float4*)(x + base + 4);
            bf8_t o = cvt8(a, b);
            *(bf8_t*)(xb + base) = o;
        }
    }
}

// ---------------- MFMA GEMM: bf16 A batched up front, B staged once, no K-loop barriers ----
// Grid = 3 col-blocks x ceil(N/64). Per block: 96 cols x 64 rows, 4 waves x 16 rows.
// Bs: 96x256 B-slice in FRAGMENT-MAJOR order (chunk F=(ks*6+j)*64+lane) -> every
// ds_read_b128 lane-linear, conflict-free (verified R9: 112K conflicts).
// A: all 8 K-chunks loaded back-to-back from bf16 xb (one latency exposure per tile).
__global__ __launch_bounds__(256) void gemm_mfma(const ushort* __restrict__ xb,
                                                 const ushort* __restrict__ wt,
                                                 const float* __restrict__ dsc,
                                                 ushort* __restrict__ t, int N) {
    __shared__ ushort Bs[BN * F_IN];   // 49152 B; reused for epilogue repack

    int tid = threadIdx.x;
    int lane = tid & 63, wave = tid >> 6;
    int cl = lane & 15, quad = lane >> 4;
    int mb = blockIdx.x / 3, cb = blockIdx.x - mb * 3;
    int gc0 = cb * BN;
    int m0 = mb * 64 + wave * 16;
    int mrow = m0 + cl;
    bool aok = (mrow < N);

    // stage B slice: 96 rows x 256 k = 3072 uint4 chunks, 12 per thread, fragment-major
    #pragma unroll
    for (int i = 0; i < 12; ++i) {
        int F = tid + i * 256;          // 0..3071
        int rem = F & 63;
        int q = rem >> 4, c = rem & 15;
        int ksj = F >> 6;               // 0..47
        int ks = ksj / 6, j = ksj - ks * 6;
        int gc = gc0 + j * 16 + c;
        *(uint4*)(Bs + (size_t)F * 8) =
            *(const uint4*)(wt + (size_t)gc * F_IN + ks * 32 + q * 8);
    }

    // batch-load all A fragments: 8 independent uint4 loads (32 VGPR)
    uint4 areg[8];
    const ushort* xp = xb + (size_t)mrow * F_IN + quad * 8;
    const uint4 zu = make_uint4(0, 0, 0, 0);
    #pragma unroll
    for (int ks = 0; ks < 8; ++ks)
        areg[ks] = aok ? *(const uint4*)(xp + ks * 32) : zu;

    f32x4 acc[6];
    #pragma unroll
    for (int j = 0; j < 6; ++j) acc[j] = (f32x4){0.f, 0.f, 0.f, 0.f};

    __syncthreads();   // B staged

    #pragma unroll
    for (int ks = 0; ks < 8; ++ks) {
        bf8_t a = *(const bf8_t*)&areg[ks];
        const ushort* bb = Bs + ((size_t)(ks * 6) * 64 + lane) * 8;
        #pragma unroll
        for (int j = 0; j < 6; ++j) {
            bf8_t b = *(const bf8_t*)(bb + j * 64 * 8);
            acc[j] = __builtin_amdgcn_mfma_f32_16x16x32_bf16(a, b, acc[j], 0, 0, 0);
        }
    }

    // epilogue: C/D layout col=cl, row=quad*4+reg. Scale, cvt, repack via LDS.
    __syncthreads();   // all B reads done before alias overwrite
    ushort* Cw = Bs + wave * (16 * CW);
    float dscv[3][4];
    #pragma unroll
    for (int ii = 0; ii < 3; ++ii)
        #pragma unroll
        for (int r = 0; r < 4; ++r) {
            int rowg = m0 + quad * 4 + r;
            dscv[ii][r] = (rowg < N) ? dsc[(size_t)ii * N + rowg] : 0.f;
        }
    #pragma unroll
    for (int j = 0; j < 6; ++j) {
        int ii = (gc0 + j * 16) / F_OUT;   // filter of this 16-col tile (uniform per tile)
        #pragma unroll
        for (int r = 0; r < 4; ++r)
            Cw[(quad * 4 + r) * CW + j * 16 + cl] = f2b(dscv[ii][r] * acc[j][r]);
    }
    // 16 rows x 12 chunks = 192 uint4 per wave; 3 per lane, coalesced
    #pragma unroll
    for (int it = 0; it < 3; ++it) {
        int idx = lane + it * 64;          // 0..191
        int r = idx / 12, ch = idx - r * 12;
        int grow = m0 + r;
        if (grow < N)
            *(uint4*)(t + (size_t)grow * TSTRIDE + gc0 + ch * 8) =
                *(const uint4*)&Cw[r * CW + ch * 8];
    }
}

// ---------------- fused SpMM + diagonal + relu + D + bias ----------------
// wave-per-row, 4 rows/block (R4-proven unroll-4). Lane l<40 owns uint4 chunk
// [8l,8l+8) of the padded 320-col t row. Edge records from bucket, shfl-broadcast.
__device__ inline void acc8(float* acc, uint4 a, float v) {
    acc[0] = fmaf(v, blo(a.x), acc[0]); acc[1] = fmaf(v, bhi(a.x), acc[1]);
    acc[2] = fmaf(v, blo(a.y), acc[2]); acc[3] = fmaf(v, bhi(a.y), acc[3]);
    acc[4] = fmaf(v, blo(a.z), acc[4]); acc[5] = fmaf(v, bhi(a.z), acc[5]);
    acc[6] = fmaf(v, blo(a.w), acc[6]); acc[7] = fmaf(v, bhi(a.w), acc[7]);
}

__global__ __launch_bounds__(256) void spmm_kernel(const ushort* __restrict__ t,
                                                   const int2* __restrict__ evs2,
                                                   const int* __restrict__ cnt,
                                                   const float* __restrict__ dsc,
                                                   const float* __restrict__ bias,
                                                   float* __restrict__ out, int N) {
    int lane = threadIdx.x & 63;
    int wave = threadIdx.x >> 6;
    int n = blockIdx.x * 4 + wave;
    if (n >= N) return;

    int deg = cnt[n];
    int mm = (deg < CAP) ? deg : CAP;
    int s = n * CAP, e = s + mm;
    int coff = (lane < 40) ? lane * 8 : 0;   // ushort offset of this lane's chunk

    float acc[8];
    #pragma unroll
    for (int j = 0; j < 8; ++j) acc[j] = 0.f;

    for (int base = s; base < e; base += 64) {
        int idx = base + lane;
        int2 q = make_int2(0, 0);
        if (idx < e) q = evs2[idx];
        int m = min(64, e - base);
        int j = 0;
        for (; j + 3 < m; j += 4) {
            int c0 = __shfl(q.x, j, 64);
            int c1 = __shfl(q.x, j + 1, 64);
            int c2 = __shfl(q.x, j + 2, 64);
            int c3 = __shfl(q.x, j + 3, 64);
            float v0 = __int_as_float(__shfl(q.y, j, 64));
            float v1 = __int_as_float(__shfl(q.y, j + 1, 64));
            float v2 = __int_as_float(__shfl(q.y, j + 2, 64));
            float v3 = __int_as_float(__shfl(q.y, j + 3, 64));
            uint4 a0 = *(const uint4*)(t + (size_t)c0 * TSTRIDE + coff);
            uint4 a1 = *(const uint4*)(t + (size_t)c1 * TSTRIDE + coff);
            uint4 a2 = *(const uint4*)(t + (size_t)c2 * TSTRIDE + coff);
            uint4 a3 = *(const uint4*)(t + (size_t)c3 * TSTRIDE + coff);
            acc8(acc, a0, v0);
            acc8(acc, a1, v1);
            acc8(acc, a2, v2);
            acc8(acc, a3, v3);
        }
        for (; j < m; ++j) {
            int c = __shfl(q.x, j, 64);
            float v = __int_as_float(__shfl(q.y, j, 64));
            uint4 a = *(const uint4*)(t + (size_t)c * TSTRIDE + coff);
            acc8(acc, a, v);
        }
    }

    // self term + relu + D scale (per-lane filter ii = lane/12 for lane<36)
    float sign = (lane < 12) ? -1.f : 1.f;
    float epsdi = EPSILON / (float)(deg + 1);   // deg includes self loop
    int ii = lane / 12;
    float dscv = (lane < 36) ? dsc[(size_t)ii * N + n] : 0.f;
    uint4 sv = *(const uint4*)(t + (size_t)n * TSTRIDE + coff);
    float se = sign * epsdi;
    float val[8];
    {
        unsigned u;
        u = sv.x; val[0] = fmaf(se, blo(u), acc[0]); val[1] = fmaf(se, bhi(u), acc[1]);
        u = sv.y; val[2] = fmaf(se, blo(u), acc[2]); val[3] = fmaf(se, bhi(u), acc[3]);
        u = sv.z; val[4] = fmaf(se, blo(u), acc[4]); val[5] = fmaf(se, bhi(u), acc[5]);
        u = sv.w; val[6] = fmaf(se, blo(u), acc[6]); val[7] = fmaf(se, bhi(u), acc[7]);
    }
    #pragma unroll
    for (int j = 0; j < 8; ++j) val[j] = fmaxf(val[j], 0.f) * dscv;

    // cross-filter reduce: out[8a+j] = val[a][j] + val[a+12][j] + val[a+24][j]
    float res[8];
    #pragma unroll
    for (int j = 0; j < 8; ++j) {
        float r1 = __shfl(val[j], lane + 12, 64);
        float r2 = __shfl(val[j], lane + 24, 64);
        res[j] = val[j] + r1 + r2;
    }
    if (lane < 12) {
        float4 b0 = *(const float4*)(bias + lane * 8);
        float4 b1 = *(const float4*)(bias + lane * 8 + 4);
        float4 o0 = make_float4(res[0] + b0.x, res[1] + b0.y, res[2] + b0.z, res[3] + b0.w);
        float4 o1 = make_float4(res[4] + b1.x, res[5] + b1.y, res[6] + b1.z, res[7] + b1.w);
        *(float4*)(out + (size_t)n * F_OUT + lane * 8) = o0;
        *(float4*)(out + (size_t)n * F_OUT + lane * 8 + 4) = o1;
    }
}

extern "C" void kernel_launch(void* const* d_in, const int* in_sizes, int n_in,
                              void* d_out, int out_size, void* d_ws, size_t ws_size,
                              hipStream_t stream) {
    const float* x    = (const float*)d_in[0];
    const float* adj  = (const float*)d_in[1];
    const float* dsc  = (const float*)d_in[2];
    const float* w    = (const float*)d_in[3];
    const float* bias = (const float*)d_in[4];
    const int*   ei   = (const int*)d_in[5];

    int E = in_sizes[1];
    int N = in_sizes[0] / F_IN;
    const int* row = ei;
    const int* col = ei + E;
    float* out = (float*)d_out;

    // workspace carve-up (256B aligned): ~84 MB total
    char* p = (char*)d_ws;
    auto take = [&](size_t bytes) {
        char* r = p;
        p += (bytes + 255) & ~(size_t)255;
        return r;
    };
    int*    cnt  = (int*)take((size_t)N * 4);
    int2*   evs2 = (int2*)take((size_t)N * CAP * 8);               // 25.6 MB
    ushort* wt   = (ushort*)take((size_t)TCOLS * F_IN * 2);
    ushort* xb   = (ushort*)take((size_t)N * F_IN * 2);            // 25.6 MB bf16 x
    ushort* t    = (ushort*)take(((size_t)N * TSTRIDE + 256) * 2); // 32 MB

    int nzero = (N + 3) / 4;
    setup_kernel<<<(NCVT + nzero + 255) / 256, 256, 0, stream>>>(w, wt, cnt, N);

    int nscat = (E / 4 + 255) / 256;
    int ncvtx = ((N * F_IN / 8) + 255) / 256;
    scatter_cvt_kernel<<<nscat + ncvtx, 256, 0, stream>>>(row, col, adj, cnt, evs2, E,
                                                          x, xb, N, nscat);
    gemm_mfma<<<3 * ((N + 63) / 64), 256, 0, stream>>>(xb, wt, dsc, t, N);
    spmm_kernel<<<(N + 3) / 4, 256, 0, stream>>>(t, evs2, cnt, dsc, bias, out, N);
}